// Round 1
// baseline (332.643 us; speedup 1.0000x reference)
//
#include <hip/hip_runtime.h>
#include <math.h>

#define TINY_EPS 1.1920928955078125e-07f  // np.finfo(np.float32).eps = 2^-23

typedef float float2v __attribute__((ext_vector_type(2)));

// ---- forced VOP3P packed fp32 ops (2 IEEE fp32 ops per issue slot) ----
// Each is per-component bit-identical to the scalar op it replaces.
static __device__ __forceinline__ float2v pk_add(float2v a, float2v b) {
    float2v d;
    asm("v_pk_add_f32 %0, %1, %2" : "=v"(d) : "v"(a), "v"(b));
    return d;
}
static __device__ __forceinline__ float2v pk_mul(float2v a, float2v b) {
    float2v d;
    asm("v_pk_mul_f32 %0, %1, %2" : "=v"(d) : "v"(a), "v"(b));
    return d;
}
static __device__ __forceinline__ float2v pk_fma(float2v a, float2v b, float2v c) {
    float2v d;
    asm("v_pk_fma_f32 %0, %1, %2, %3" : "=v"(d) : "v"(a), "v"(b), "v"(c));
    return d;
}
static __device__ __forceinline__ void pk_fma_acc(float2v& c, float2v a, float2v b) {
    asm("v_pk_fma_f32 %0, %1, %2, %0" : "+v"(c) : "v"(a), "v"(b));
}

struct PkConsts {
    float2v neg1, half, neghalf, neg4, quarter;
};

// custom_round per component: floor((x - copysign(TINY,x)) + 0.5).
// pk_fma(cs,-1,v) == fl(v-cs) (single rounding, identical to IEEE sub).
static __device__ __forceinline__ float2v croundv(float2v v, const PkConsts& C) {
#pragma clang fp contract(off)
    float2v cs;
    cs.x = copysignf(TINY_EPS, v.x);
    cs.y = copysignf(TINY_EPS, v.y);
    float2v t = pk_fma(cs, C.neg1, v);   // v - cs
    t = pk_add(t, C.half);               // + 0.5
    float2v f;
    f.x = floorf(t.x);
    f.y = floorf(t.y);
    return f;
}

// One D8 branch candidate: y = f + parity-masked g_x flip. Distances are NOT
// computed here — the caller computes them from the ORIGINAL x (ref dataflow).
static __device__ __forceinline__ void d8_candidate(const float2v in[4], float2v y[4],
                                                    const PkConsts& C) {
#pragma clang fp contract(off)
    float2v f[4], w[4];
#pragma unroll
    for (int p = 0; p < 4; ++p) {
        f[p] = croundv(in[p], C);
        w[p] = pk_fma(f[p], C.neg1, in[p]);   // in - f (exact)
    }

    // parity of the integer sum — exact small ints, order-free
    float2v sp = pk_add(pk_add(f[0], f[1]), pk_add(f[2], f[3]));
    float s = sp.x + sp.y;
    int odd = ((int)s) & 1;

    // argmax |w|, FIRST index on ties — tournament tree (same 7 compares as
    // the descending scan, but dep-chain depth 3 instead of 7).
    // Left side wins ties (>=), so the winner is the lowest-indexed maximum,
    // identical to jnp.argmax first-occurrence semantics (proof: each merge
    // keeps the lower-index subtree's winner on ties; maxima in the left
    // subtree always have lower indices than any in the right).
    float v01, v23, v45, v67; int k01, k23, k45, k67;
    { bool ge = fabsf(w[0].x) >= fabsf(w[0].y); v01 = ge ? w[0].x : w[0].y; k01 = ge ? 0 : 1; }
    { bool ge = fabsf(w[1].x) >= fabsf(w[1].y); v23 = ge ? w[1].x : w[1].y; k23 = ge ? 2 : 3; }
    { bool ge = fabsf(w[2].x) >= fabsf(w[2].y); v45 = ge ? w[2].x : w[2].y; k45 = ge ? 4 : 5; }
    { bool ge = fabsf(w[3].x) >= fabsf(w[3].y); v67 = ge ? w[3].x : w[3].y; k67 = ge ? 6 : 7; }
    float va, vb; int ka, kb;
    { bool ge = fabsf(v01) >= fabsf(v23); va = ge ? v01 : v23; ka = ge ? k01 : k23; }
    { bool ge = fabsf(v45) >= fabsf(v67); vb = ge ? v45 : v67; kb = ge ? k45 : k67; }
    int k; float wk;
    { bool ge = fabsf(va) >= fabsf(vb); wk = ge ? va : vb; k = ge ? ka : kb; }

    // step = sign(wk) for wk!=0; for wk==0: all |w|==0 so k==0 (all-ties pick
    // the leftmost leaf) and the tie x-value is in[0].x, never -0.0.
    float tsel = (wk != 0.0f) ? wk : -in[0].x;
    float sf = __int_as_float(0x3f800000 | (__float_as_int(tsel) & 0x80000000u));
    float sfm = odd ? sf : 0.0f;          // flip only when parity is odd

#pragma unroll
    for (int p = 0; p < 4; ++p) {
        float2v c;
        c.x = (k == 2 * p)     ? sfm : 0.0f;
        c.y = (k == 2 * p + 1) ? sfm : 0.0f;
        y[p] = pk_add(f[p], c);
    }
}

static __device__ __forceinline__ void closest_point_E8v(const float2v x[4], float2v y[4],
                                                         const PkConsts& C) {
#pragma clang fp contract(off)
    float2v y0[4], y1[4], xs[4];
    d8_candidate(x, y0, C);
#pragma unroll
    for (int p = 0; p < 4; ++p) xs[p] = pk_add(x[p], C.neghalf);   // x - 0.5
    d8_candidate(xs, y1, C);
#pragma unroll
    for (int p = 0; p < 4; ++p) y1[p] = pk_add(y1[p], C.half);     // (cand)+0.5

    // Distances from the ORIGINAL x; packed subs/squares, scalar tree adds in
    // numpy's exact pairwise order — vector-element pairs ARE the base pairs.
    float2v q0[4], q1[4];
#pragma unroll
    for (int p = 0; p < 4; ++p) {
        float2v e0 = pk_fma(y0[p], C.neg1, x[p]);  // x - y0
        q0[p] = pk_mul(e0, e0);
        float2v e1 = pk_fma(y1[p], C.neg1, x[p]);  // x - y1
        q1[p] = pk_mul(e1, e1);
    }
    float D0 = ((q0[0].x + q0[0].y) + (q0[1].x + q0[1].y)) +
               ((q0[2].x + q0[2].y) + (q0[3].x + q0[3].y));
    float D1 = ((q1[0].x + q1[0].y) + (q1[1].x + q1[1].y)) +
               ((q1[2].x + q1[2].y) + (q1[3].x + q1[3].y));
    bool pick0 = (D0 < D1);               // tie -> y1, as in ref
#pragma unroll
    for (int p = 0; p < 4; ++p) {
        float2v r;
        r.x = pick0 ? y0[p].x : y1[p].x;
        r.y = pick0 ? y0[p].y : y1[p].y;
        y[p] = r;
    }
}

__global__ __launch_bounds__(256)
void lattice_quant_kernel(const float* __restrict__ x,
                          const float* __restrict__ beta_p,
                          const float* __restrict__ eps,
                          float* __restrict__ out, int n) {
#pragma clang fp contract(off)
    int row = blockIdx.x * blockDim.x + threadIdx.x;
    if (row >= n) return;
    float beta = beta_p[0];

    PkConsts C;
    C.neg1    = (float2v){-1.0f, -1.0f};
    C.half    = (float2v){ 0.5f,  0.5f};
    C.neghalf = (float2v){-0.5f, -0.5f};
    C.neg4    = (float2v){-4.0f, -4.0f};
    C.quarter = (float2v){ 0.25f, 0.25f};

    const float4* px = (const float4*)(x + (size_t)row * 8);
    float4 a0 = px[0], a1 = px[1];
    const float4* pe = (const float4*)eps;
    float4 e0 = pe[0], e1 = pe[1];
    float2v eps2[4] = { {e0.x, e0.y}, {e0.z, e0.w}, {e1.x, e1.y}, {e1.z, e1.w} };

    float2v xl[4] = { {a0.x, a0.y}, {a0.z, a0.w}, {a1.x, a1.y}, {a1.z, a1.w} };
    if (beta != 1.0f) {                   // wave-uniform; beta==1 skips divs
#pragma unroll
        for (int p = 0; p < 4; ++p) { xl[p].x = xl[p].x / beta; xl[p].y = xl[p].y / beta; }
    }

    float2v xhat[4];

    float wgt = 1.0f;
#pragma unroll
    for (int l = 0; l < 3; ++l) {
        // ---- encode: quantize to E8 ----
        float2v xin[4], lat[4];
#pragma unroll
        for (int p = 0; p < 4; ++p) xin[p] = pk_add(xl[p], eps2[p]);
        closest_point_E8v(xin, lat, C);

        // u = lat @ G_inv via forward substitution (exact fp32 == ref matmul)
        float u0 = 0.5f * lat[0].x;
        float u1 = lat[0].y + u0;
        float u2 = lat[1].x + u1;
        float u3 = lat[1].y + u2;
        float u4 = lat[2].x + u3;
        float u5 = lat[2].y + u4;
        float u6 = lat[3].x + u5;
        float s6 = ((u0 + u1) + (u2 + u3)) + ((u4 + u5) + u6);
        float u7 = 2.0f * lat[3].y - s6;
        float2v uv[4] = { {u0, u1}, {u2, u3}, {u4, u5}, {u6, u7} };

        // b = custom_round(fmod(u, 4)); fmod exact on quarter grid; the fma
        // is exact-by-proof (trunc*4 exact), so fused == ref's separate ops.
        // NOTE: u contains half-integers (u0 = lat0/2 with odd lat0), so the
        // croundv here is NOT removable (cround(3.5)==4 quirk included).
        float2v b[4];
#pragma unroll
        for (int p = 0; p < 4; ++p) {
            float2v q = pk_mul(uv[p], C.quarter);
            float2v t4; t4.x = truncf(q.x); t4.y = truncf(q.y);
            float2v m = pk_fma(t4, C.neg4, uv[p]);
            b[p] = croundv(m, C);
        }

        // ---- decode this layer: Gb = b @ rows (sparse, exact ints) ----
        float b0 = b[0].x, b1 = b[0].y, b2 = b[1].x, b3 = b[1].y;
        float b4 = b[2].x, b5 = b[2].y, b6 = b[3].x, b7 = b[3].y;
        float h = 0.5f * b7;
        float2v Gb[4];
        Gb[0].x = 2.0f * b0 - b1 + h;
        Gb[0].y = b1 - b2 + h;
        Gb[1].x = b2 - b3 + h;
        Gb[1].y = b3 - b4 + h;
        Gb[2].x = b4 - b5 + h;
        Gb[2].y = b5 - b6 + h;
        Gb[3].x = b6 + h;
        Gb[3].y = h;

        float2v gq[4], cp[4];
#pragma unroll
        for (int p = 0; p < 4; ++p) gq[p] = pk_mul(Gb[p], C.quarter);
        closest_point_E8v(gq, cp, C);

        float2v wv = {wgt, wgt};
#pragma unroll
        for (int p = 0; p < 4; ++p) {
            float2v xi = pk_fma(cp[p], C.neg4, Gb[p]);  // Gb - 4*cp (exact)
            if (l == 0) {
                // layer 0: ref computes 0 + 1*xi = xi bitwise (xi is never -0:
                // exact cancellation in RN yields +0), so a plain copy is
                // bit-exact and skips an un-foldable inline-asm FMA.
                xhat[p] = xi;
            } else {
                pk_fma_acc(xhat[p], xi, wv);            // += wgt*xi (exact)
            }
        }

        // next layer input: lat / Q (exact)
#pragma unroll
        for (int p = 0; p < 4; ++p) xl[p] = pk_mul(lat[p], C.quarter);
        wgt *= 4.0f;
    }

    // epilogue: beta==1 -> x*1 == x bitwise, skip the mul (wave-uniform)
    float2v o[4];
    if (beta != 1.0f) {
        float2v bv = {beta, beta};
#pragma unroll
        for (int p = 0; p < 4; ++p) o[p] = pk_mul(xhat[p], bv);
    } else {
#pragma unroll
        for (int p = 0; p < 4; ++p) o[p] = xhat[p];
    }
    float4 o0, o1;
    o0.x = o[0].x; o0.y = o[0].y; o0.z = o[1].x; o0.w = o[1].y;
    o1.x = o[2].x; o1.y = o[2].y; o1.z = o[3].x; o1.w = o[3].y;
    float4* po = (float4*)(out + (size_t)row * 8);
    po[0] = o0; po[1] = o1;
}

extern "C" void kernel_launch(void* const* d_in, const int* in_sizes, int n_in,
                              void* d_out, int out_size, void* d_ws, size_t ws_size,
                              hipStream_t stream) {
    const float* x      = (const float*)d_in[0];
    const float* beta_p = (const float*)d_in[1];
    // d_in[2] = G, d_in[3] = G_inv — structure hardcoded (fixed by reference)
    const float* eps    = (const float*)d_in[4];
    float* out = (float*)d_out;
    int n = in_sizes[0] / 8;
    int block = 256;
    int grid = (n + block - 1) / block;
    lattice_quant_kernel<<<grid, block, 0, stream>>>(x, beta_p, eps, out, n);
}

// Round 2
// 332.609 us; speedup vs baseline: 1.0001x; 1.0001x over previous
//
#include <hip/hip_runtime.h>
#include <math.h>

#define TINY_EPS 1.1920928955078125e-07f  // np.finfo(np.float32).eps = 2^-23

typedef float float2v __attribute__((ext_vector_type(2)));

// Native vector ops: on gfx950 (hasPackedFP32Ops) LLVM selects v_pk_add_f32 /
// v_pk_mul_f32 / v_pk_fma_f32 directly from <2 x float> IR, with inline-const
// operands and neg/abs modifiers folded — no asm marshaling movs.
// All FP stays IEEE-exact: fp contract(off) everywhere; explicit single-rounded
// FMA only via __builtin_elementwise_fma where exactness is proven.
static __device__ __forceinline__ float2v vfma(float2v a, float2v b, float2v c) {
    return __builtin_elementwise_fma(a, b, c);
}
static __device__ __forceinline__ float2v splat(float s) { return (float2v){s, s}; }

// custom_round per component: floor((x - copysign(TINY,x)) + 0.5).
// (v - cs) is a single IEEE sub == ref's x - sign(x)*TINY (sign(0) quirk safe:
// cround(+/-0)=0 both ways).
static __device__ __forceinline__ float2v croundv(float2v v) {
#pragma clang fp contract(off)
    float2v cs = { copysignf(TINY_EPS, v.x), copysignf(TINY_EPS, v.y) };
    float2v t = (v - cs) + splat(0.5f);
    return (float2v){ floorf(t.x), floorf(t.y) };
}

// One D8 branch candidate: y = f + parity-masked g_x flip (+0.5 coset bias
// folded into the select constants when SHIFTED — bit-exact: f and c are
// integers, so f+(c+0.5) == (f+c)+0.5 exactly).
template <bool SHIFTED>
static __device__ __forceinline__ void d8_candidate(const float2v in[4], float2v y[4]) {
#pragma clang fp contract(off)
    float2v f[4], w[4];
#pragma unroll
    for (int p = 0; p < 4; ++p) {
        f[p] = croundv(in[p]);
        w[p] = in[p] - f[p];              // exact (Sterbenz-type)
    }

    // parity of the integer sum — exact small ints, order-free
    float2v sp = (f[0] + f[1]) + (f[2] + f[3]);
    float s = sp.x + sp.y;
    int odd = ((int)s) & 1;

    // argmax |w|, FIRST index on ties — tournament tree (dep depth 3).
    // Left wins ties (>=) => lowest-indexed maximum, == jnp.argmax semantics.
    float v01, v23, v45, v67; int k01, k23, k45, k67;
    { bool ge = fabsf(w[0].x) >= fabsf(w[0].y); v01 = ge ? w[0].x : w[0].y; k01 = ge ? 0 : 1; }
    { bool ge = fabsf(w[1].x) >= fabsf(w[1].y); v23 = ge ? w[1].x : w[1].y; k23 = ge ? 2 : 3; }
    { bool ge = fabsf(w[2].x) >= fabsf(w[2].y); v45 = ge ? w[2].x : w[2].y; k45 = ge ? 4 : 5; }
    { bool ge = fabsf(w[3].x) >= fabsf(w[3].y); v67 = ge ? w[3].x : w[3].y; k67 = ge ? 6 : 7; }
    float va, vb; int ka, kb;
    { bool ge = fabsf(v01) >= fabsf(v23); va = ge ? v01 : v23; ka = ge ? k01 : k23; }
    { bool ge = fabsf(v45) >= fabsf(v67); vb = ge ? v45 : v67; kb = ge ? k45 : k67; }
    int k; float wk;
    { bool ge = fabsf(va) >= fabsf(vb); wk = ge ? va : vb; k = ge ? ka : kb; }

    // step = sign(wk) for wk!=0; for wk==0 all |w|==0 so k==0 and the tie
    // x-value is in[0].x (never -0.0 on any reachable path).
    float tsel = (wk != 0.0f) ? wk : -in[0].x;
    float sf = __int_as_float(0x3f800000 | (__float_as_int(tsel) & 0x80000000u));
    float sfm = odd ? sf : 0.0f;          // flip only when parity is odd

    const float bias = SHIFTED ? 0.5f : 0.0f;
    const float fb   = SHIFTED ? (sfm + 0.5f) : sfm;   // exact
#pragma unroll
    for (int p = 0; p < 4; ++p) {
        float2v c;
        c.x = (k == 2 * p)     ? fb : bias;
        c.y = (k == 2 * p + 1) ? fb : bias;
        y[p] = f[p] + c;                   // integers (+bias): exact
    }
}

static __device__ __forceinline__ void closest_point_E8v(const float2v x[4], float2v y[4]) {
#pragma clang fp contract(off)
    float2v y0[4], y1[4], xs[4];
    d8_candidate<false>(x, y0);
#pragma unroll
    for (int p = 0; p < 4; ++p) xs[p] = x[p] - splat(0.5f);
    d8_candidate<true>(xs, y1);            // (cand)+0.5 already folded in

    // Distances from the ORIGINAL x; packed subs/squares, scalar tree adds in
    // numpy's exact pairwise order — vector-element pairs ARE the base pairs.
    float2v q0[4], q1[4];
#pragma unroll
    for (int p = 0; p < 4; ++p) {
        float2v e0 = x[p] - y0[p];
        q0[p] = e0 * e0;
        float2v e1 = x[p] - y1[p];
        q1[p] = e1 * e1;
    }
    float D0 = ((q0[0].x + q0[0].y) + (q0[1].x + q0[1].y)) +
               ((q0[2].x + q0[2].y) + (q0[3].x + q0[3].y));
    float D1 = ((q1[0].x + q1[0].y) + (q1[1].x + q1[1].y)) +
               ((q1[2].x + q1[2].y) + (q1[3].x + q1[3].y));
    bool pick0 = (D0 < D1);               // tie -> y1, as in ref
#pragma unroll
    for (int p = 0; p < 4; ++p) {
        float2v r;
        r.x = pick0 ? y0[p].x : y1[p].x;
        r.y = pick0 ? y0[p].y : y1[p].y;
        y[p] = r;
    }
}

__global__ __launch_bounds__(256)
void lattice_quant_kernel(const float* __restrict__ x,
                          const float* __restrict__ beta_p,
                          const float* __restrict__ eps,
                          float* __restrict__ out, int n) {
#pragma clang fp contract(off)
    int row = blockIdx.x * blockDim.x + threadIdx.x;
    if (row >= n) return;
    float beta = beta_p[0];

    const float4* px = (const float4*)(x + (size_t)row * 8);
    float4 a0 = px[0], a1 = px[1];
    const float4* pe = (const float4*)eps;
    float4 e0 = pe[0], e1 = pe[1];
    float2v eps2[4] = { {e0.x, e0.y}, {e0.z, e0.w}, {e1.x, e1.y}, {e1.z, e1.w} };

    float2v xl[4] = { {a0.x, a0.y}, {a0.z, a0.w}, {a1.x, a1.y}, {a1.z, a1.w} };
    if (beta != 1.0f) {                   // wave-uniform; beta==1 skips divs
#pragma unroll
        for (int p = 0; p < 4; ++p) { xl[p].x = xl[p].x / beta; xl[p].y = xl[p].y / beta; }
    }

    float2v xhat[4];

    float wgt = 1.0f;
#pragma unroll
    for (int l = 0; l < 3; ++l) {
        // ---- encode: quantize to E8 ----
        float2v xin[4], lat[4];
#pragma unroll
        for (int p = 0; p < 4; ++p) xin[p] = xl[p] + eps2[p];
        closest_point_E8v(xin, lat);

        // u = lat @ G_inv via forward substitution (exact fp32 == ref matmul)
        float u0 = 0.5f * lat[0].x;
        float u1 = lat[0].y + u0;
        float u2 = lat[1].x + u1;
        float u3 = lat[1].y + u2;
        float u4 = lat[2].x + u3;
        float u5 = lat[2].y + u4;
        float u6 = lat[3].x + u5;
        float s6 = ((u0 + u1) + (u2 + u3)) + ((u4 + u5) + u6);
        float u7 = fmaf(2.0f, lat[3].y, -s6);   // 2*lat7 exact -> == mul+sub
        float2v uv[4] = { {u0, u1}, {u2, u3}, {u4, u5}, {u6, u7} };

        // b = custom_round(fmod(u, 4)); fmod exact on quarter grid; the fma
        // is exact-by-proof (trunc*4 exact), so fused == ref's separate ops.
        // NOTE: u contains half/quarter-integers (u0 = lat0/2), so the croundv
        // here is NOT removable (cround(3.5)==4 quirk included).
        float2v b[4];
#pragma unroll
        for (int p = 0; p < 4; ++p) {
            float2v q = uv[p] * splat(0.25f);            // exact (pow2)
            float2v t4 = { truncf(q.x), truncf(q.y) };
            float2v m = vfma(t4, splat(-4.0f), uv[p]);   // == fmod(u,4) exact
            b[p] = croundv(m);
        }

        // ---- decode this layer: Gb = b @ rows (sparse, exact ints) ----
        float b0 = b[0].x, b1 = b[0].y, b2 = b[1].x, b3 = b[1].y;
        float b4 = b[2].x, b5 = b[2].y, b6 = b[3].x, b7 = b[3].y;
        float h = 0.5f * b7;
        float2v Gb[4];
        Gb[0].x = 2.0f * b0 - b1 + h;
        Gb[0].y = b1 - b2 + h;
        Gb[1].x = b2 - b3 + h;
        Gb[1].y = b3 - b4 + h;
        Gb[2].x = b4 - b5 + h;
        Gb[2].y = b5 - b6 + h;
        Gb[3].x = b6 + h;
        Gb[3].y = h;

        float2v gq[4], cp[4];
#pragma unroll
        for (int p = 0; p < 4; ++p) gq[p] = Gb[p] * splat(0.25f);
        closest_point_E8v(gq, cp);

#pragma unroll
        for (int p = 0; p < 4; ++p) {
            float2v xi = vfma(cp[p], splat(-4.0f), Gb[p]);  // Gb - 4*cp (exact)
            if (l == 0) {
                // layer 0: ref computes 0 + 1*xi = xi bitwise (xi never -0),
                // so a plain copy is bit-exact.
                xhat[p] = xi;
            } else {
                xhat[p] = vfma(xi, splat(wgt), xhat[p]);    // += wgt*xi (exact)
            }
        }

        // next layer input: lat / Q (exact)
#pragma unroll
        for (int p = 0; p < 4; ++p) xl[p] = lat[p] * splat(0.25f);
        wgt *= 4.0f;
    }

    // epilogue: beta==1 -> x*1 == x bitwise, skip the mul (wave-uniform)
    float2v o[4];
    if (beta != 1.0f) {
        float2v bv = splat(beta);
#pragma unroll
        for (int p = 0; p < 4; ++p) o[p] = xhat[p] * bv;
    } else {
#pragma unroll
        for (int p = 0; p < 4; ++p) o[p] = xhat[p];
    }
    float4 o0, o1;
    o0.x = o[0].x; o0.y = o[0].y; o0.z = o[1].x; o0.w = o[1].y;
    o1.x = o[2].x; o1.y = o[2].y; o1.z = o[3].x; o1.w = o[3].y;
    float4* po = (float4*)(out + (size_t)row * 8);
    po[0] = o0; po[1] = o1;
}

extern "C" void kernel_launch(void* const* d_in, const int* in_sizes, int n_in,
                              void* d_out, int out_size, void* d_ws, size_t ws_size,
                              hipStream_t stream) {
    const float* x      = (const float*)d_in[0];
    const float* beta_p = (const float*)d_in[1];
    // d_in[2] = G, d_in[3] = G_inv — structure hardcoded (fixed by reference)
    const float* eps    = (const float*)d_in[4];
    float* out = (float*)d_out;
    int n = in_sizes[0] / 8;
    int block = 256;
    int grid = (n + block - 1) / block;
    lattice_quant_kernel<<<grid, block, 0, stream>>>(x, beta_p, eps, out, n);
}